// Round 4
// baseline (301.755 us; speedup 1.0000x reference)
//
#include <hip/hip_runtime.h>

// ---------- problem constants ----------
#define BATCH   16
#define LIN     320000
#define LP      322048          // LIN + 2048 (reflect pad 1024 each side)
#define TFR     626             // frames per batch
#define MTOT    (BATCH*TFR)     // 10016
#define KD      2048            // N_FFT
#define KOUT    1025            // N_FFT/2+1
#define NPACK   2048            // packed cols: [0,1024) real | [1024,2048) imag
#define IMAG_OFF ((long)MTOT*KOUT)   // 10266400

typedef __attribute__((ext_vector_type(8))) short short8;
typedef __attribute__((ext_vector_type(4))) float float4v;
typedef unsigned short ushort_t;

#define XP_BLOCKS   ((BATCH*LP)/256)   // 20128
#define WBT_BLOCKS  (64*64)            // 4096
#define NYQ_BLOCKS  (MTOT/4)           // 2504: 4 waves/block, ONE FRAME PER WAVE

static __device__ __forceinline__ ushort_t f32_to_bf16(float f) {
    union { float f; unsigned u; } un; un.f = f;
    unsigned r = un.u + 0x7fffu + ((un.u >> 16) & 1u);   // RNE
    return (ushort_t)(r >> 16);
}

static __device__ __forceinline__ void async_copy16(const void* g, void* l) {
    __builtin_amdgcn_global_load_lds(
        (const __attribute__((address_space(1))) void*)g,
        (__attribute__((address_space(3))) void*)l, 16, 0, 0);
}

// ---------- fused prep: xp build | W^T pack | Nyquist column ----------
__global__ void prep(const float* __restrict__ x,
                     const float* __restrict__ wr,
                     const float* __restrict__ wi,
                     ushort_t* __restrict__ xp,
                     ushort_t* __restrict__ wbt,
                     float* __restrict__ out) {
    __shared__ ushort_t tile[32][33];
    const int blk = blockIdx.x;

    if (blk < XP_BLOCKS) {
        // reflect-pad fp32 x -> bf16 xp (BATCH x LP)
        int i = blk * 256 + threadIdx.x;
        int b = i / LP;
        int p = i - b * LP;
        int j = p - 1024;
        if (j < 0) j = -j;
        else if (j >= LIN) j = 2 * LIN - 2 - j;
        xp[i] = f32_to_bf16(x[b * LIN + j]);
    } else if (blk < XP_BLOCKS + WBT_BLOCKS) {
        // pack W^T n-major bf16: wbt[n][k], n<1024 real, else imag(n-1024)
        int t = blk - XP_BLOCKS;
        int n0 = (t & 63) * 32;
        int k0 = (t >> 6) * 32;
        int tx = threadIdx.x & 31;
        int ty = threadIdx.x >> 5;            // 0..7
        int n = n0 + tx;
#pragma unroll
        for (int i = 0; i < 4; ++i) {
            int k = k0 + ty + i * 8;
            float v = (n < 1024) ? wr[k * KOUT + n] : wi[k * KOUT + (n - 1024)];
            tile[ty + i * 8][tx] = f32_to_bf16(v);
        }
        __syncthreads();
#pragma unroll
        for (int i = 0; i < 4; ++i)
            wbt[(n0 + ty + i * 8) * KD + k0 + tx] = tile[tx][ty + i * 8];
    } else {
        // Nyquist (k=1024): exact fp32 dot per frame, one wave per frame;
        // imag-Nyquist == 0 analytically (sin(pi*n) ~ 1e-13)
        int wave = threadIdx.x >> 6, lane = threadIdx.x & 63;
        int m = (blk - XP_BLOCKS - WBT_BLOCKS) * 4 + wave;   // covers 0..10015
        if (m >= MTOT) return;
        int b = m / TFR, t = m - b * TFR;
        float s = 0.f;
        for (int n = lane; n < KD; n += 64) {
            int p = t * 512 + n - 1024;
            if (p < 0) p = -p;
            else if (p >= LIN) p = 2 * LIN - 2 - p;
            s += x[b * LIN + p] * wr[n * KOUT + 1024];
        }
#pragma unroll
        for (int off = 32; off; off >>= 1) s += __shfl_down(s, off);
        if (lane == 0) {
            out[(long)m * KOUT + 1024] = s;
            out[IMAG_OFF + (long)m * KOUT + 1024] = 0.f;
        }
    }
}

// ---------- main GEMM: 128x128 tile, BK=64, XOR-swizzled LDS ----------
__global__ __launch_bounds__(256) void stft_gemm(const ushort_t* __restrict__ xp,
                                                 const ushort_t* __restrict__ wbt,
                                                 float* __restrict__ out) {
    __shared__ __align__(16) ushort_t As[128 * 64];   // 16 KB, row*128B, swizzled granules
    __shared__ __align__(16) ushort_t Bs[128 * 64];   // 16 KB

    const int tid = threadIdx.x;
    const int m0 = blockIdx.x * 128;   // x = m-tile (79)
    const int n0 = blockIdx.y * 128;   // y = n-tile (16)

    // staging source offsets: slot s = j*256+tid -> row=s>>3, phys granule=s&7,
    // logical granule g = (s&7) ^ (row&7); source k-offset = g*8
    int baseA[4], baseB[4];
#pragma unroll
    for (int j = 0; j < 4; ++j) {
        int slot = j * 256 + tid;
        int row  = slot >> 3;
        int g    = (slot & 7) ^ (row & 7);
        int m = m0 + row; if (m > MTOT - 1) m = MTOT - 1;   // clamp; stores guarded
        int b = m / TFR;
        int t = m - b * TFR;
        baseA[j] = b * LP + t * 512 + g * 8;
        baseB[j] = (n0 + row) * KD + g * 8;                 // n0+row < 2048 always
    }

    const int wave = tid >> 6;
    const int lane = tid & 63;
    const int wm = (wave >> 1) * 64;
    const int wn = (wave & 1) * 64;
    const int lm = lane & 15;
    const int quad = lane >> 4;

    float4v acc[4][4];
#pragma unroll
    for (int mi = 0; mi < 4; ++mi)
#pragma unroll
        for (int ni = 0; ni < 4; ++ni)
            acc[mi][ni] = (float4v){0.f, 0.f, 0.f, 0.f};

    for (int k0 = 0; k0 < KD; k0 += 64) {
        __syncthreads();                          // prior ds_reads done
#pragma unroll
        for (int j = 0; j < 4; ++j)
            async_copy16(xp + baseA[j] + k0, (char*)As + (j * 256 + tid) * 16);
#pragma unroll
        for (int j = 0; j < 4; ++j)
            async_copy16(wbt + baseB[j] + k0, (char*)Bs + (j * 256 + tid) * 16);
        __syncthreads();                          // drains vmcnt

#pragma unroll
        for (int kk = 0; kk < 2; ++kk) {
            short8 af[4], bf[4];
#pragma unroll
            for (int mi = 0; mi < 4; ++mi) {
                int row = wm + mi * 16 + lm;
                int pg  = (kk * 4 + quad) ^ (row & 7);
                af[mi] = *(const short8*)&As[row * 64 + pg * 8];
            }
#pragma unroll
            for (int ni = 0; ni < 4; ++ni) {
                int row = wn + ni * 16 + lm;
                int pg  = (kk * 4 + quad) ^ (row & 7);
                bf[ni] = *(const short8*)&Bs[row * 64 + pg * 8];
            }
#pragma unroll
            for (int mi = 0; mi < 4; ++mi)
#pragma unroll
                for (int ni = 0; ni < 4; ++ni)
                    acc[mi][ni] = __builtin_amdgcn_mfma_f32_16x16x32_bf16(
                        af[mi], bf[ni], acc[mi][ni], 0, 0, 0);
        }
    }

    // epilogue: C/D layout col=lane&15 (n), row=quad*4+reg (m); fp32 out
#pragma unroll
    for (int mi = 0; mi < 4; ++mi) {
#pragma unroll
        for (int ni = 0; ni < 4; ++ni) {
            int n = n0 + wn + ni * 16 + lm;           // < 2048 always
            long nbase = (n < 1024) ? (long)n : (IMAG_OFF + (n - 1024));
#pragma unroll
            for (int rg = 0; rg < 4; ++rg) {
                int m = m0 + wm + mi * 16 + quad * 4 + rg;
                if (m < MTOT)
                    out[nbase + (long)m * KOUT] = acc[mi][ni][rg];
            }
        }
    }
}

extern "C" void kernel_launch(void* const* d_in, const int* in_sizes, int n_in,
                              void* d_out, int out_size, void* d_ws, size_t ws_size,
                              hipStream_t stream) {
    const float* x  = (const float*)d_in[0];     // fp32 (16, 320000)
    const float* wr = (const float*)d_in[1];     // fp32 (2048, 1025)
    const float* wi = (const float*)d_in[2];     // fp32 (2048, 1025)
    float* out = (float*)d_out;                  // fp32, 2*16*626*1025

    ushort_t* xp  = (ushort_t*)d_ws;             // 16*322048 bf16 = 10.3 MB
    ushort_t* wbt = xp + BATCH * LP;             // 2048*2048 bf16 =  8.4 MB

    prep<<<XP_BLOCKS + WBT_BLOCKS + NYQ_BLOCKS, 256, 0, stream>>>(x, wr, wi, xp, wbt, out);

    dim3 grid(79, 16);                           // x = m-tile, y = n-tile
    stft_gemm<<<grid, 256, 0, stream>>>(xp, wbt, out);
}

// Round 5
// 222.672 us; speedup vs baseline: 1.3552x; 1.3552x over previous
//
#include <hip/hip_runtime.h>

// ---------- problem constants ----------
#define BATCH   16
#define LIN     320000
#define LP      322048          // LIN + 2048 (reflect pad 1024 each side)
#define TFR     626             // frames per batch
#define MTOT    (BATCH*TFR)     // 10016
#define KD      2048            // N_FFT
#define KOUT    1025            // N_FFT/2+1
// packed cols: n<1025 -> real k=n ; n in [1025,2048) -> imag k=n-1024 (1..1023)
// imag k=0 and k=1024 are analytically ~0 -> written as zeros in prep
#define IMAG_OFF ((long)MTOT*KOUT)   // 10266400

typedef __attribute__((ext_vector_type(8))) short short8;
typedef __attribute__((ext_vector_type(4))) float float4v;
typedef unsigned short ushort_t;

#define XP_BLOCKS   ((BATCH*LP)/2048)        // 2516 (8 elems/thread)
#define WBT_BLOCKS  ((KD/64)*(KD/64))        // 1024 (64x64 tiles)
#define ZB_BLOCKS   ((2*MTOT+255)/256)       // 79  (imag k=0,1024 zeros)

static __device__ __forceinline__ ushort_t f32_to_bf16(float f) {
    union { float f; unsigned u; } un; un.f = f;
    unsigned r = un.u + 0x7fffu + ((un.u >> 16) & 1u);   // RNE
    return (ushort_t)(r >> 16);
}

static __device__ __forceinline__ void async_copy16(const void* g, void* l) {
    __builtin_amdgcn_global_load_lds(
        (const __attribute__((address_space(1))) void*)g,
        (__attribute__((address_space(3))) void*)l, 16, 0, 0);
}

// ---------- fused prep: xp build | W^T pack | imag edge-column zeros --------
__global__ void prep(const float* __restrict__ x,
                     const float* __restrict__ wr,
                     const float* __restrict__ wi,
                     ushort_t* __restrict__ xp,
                     ushort_t* __restrict__ wbt,
                     float* __restrict__ out) {
    __shared__ ushort_t tile[64][65];
    const int blk = blockIdx.x;

    if (blk < XP_BLOCKS) {
        // reflect-pad fp32 x -> bf16 xp, 8 elements per thread
        int i0 = blk * 2048 + threadIdx.x * 8;
        int b  = i0 / LP;
        int p0 = i0 - b * LP;
        short8 v;
        if (p0 >= 1024 && p0 + 8 <= 1024 + LIN) {        // interior fast path
            const float* src = x + b * LIN + (p0 - 1024);
            float4v u0 = *(const float4v*)src;
            float4v u1 = *(const float4v*)(src + 4);
#pragma unroll
            for (int e = 0; e < 4; ++e) { v[e] = (short)f32_to_bf16(u0[e]); v[4+e] = (short)f32_to_bf16(u1[e]); }
        } else {
#pragma unroll
            for (int e = 0; e < 8; ++e) {
                int i = i0 + e;
                int bb = i / LP;
                int j = (i - bb * LP) - 1024;
                if (j < 0) j = -j;
                else if (j >= LIN) j = 2 * LIN - 2 - j;
                v[e] = (short)f32_to_bf16(x[bb * LIN + j]);
            }
        }
        *(short8*)(xp + i0) = v;
    } else if (blk < XP_BLOCKS + WBT_BLOCKS) {
        // pack W^T n-major bf16 via 64x64 LDS transpose tile
        int t  = blk - XP_BLOCKS;
        int n0 = (t & 31) * 64;
        int k0 = (t >> 5) * 64;
        int tx = threadIdx.x & 63;
        int ty = threadIdx.x >> 6;               // 0..3
        int n  = n0 + tx;
#pragma unroll
        for (int i = 0; i < 16; ++i) {
            int k = k0 + ty + i * 4;
            float v = (n < KOUT) ? wr[k * KOUT + n] : wi[k * KOUT + (n - 1024)];
            tile[ty + i * 4][tx] = f32_to_bf16(v);
        }
        __syncthreads();
#pragma unroll
        for (int i = 0; i < 16; ++i) {
            int row = ty + i * 4;                // n within tile
            wbt[(n0 + row) * KD + k0 + tx] = tile[tx][row];
        }
    } else {
        // imag k=0 and k=1024 columns are ~1e-12 -> exact zeros
        int idx = (blk - XP_BLOCKS - WBT_BLOCKS) * 256 + threadIdx.x;
        if (idx < 2 * MTOT) {
            int m = (idx < MTOT) ? idx : (idx - MTOT);
            int k = (idx < MTOT) ? 0 : 1024;
            out[IMAG_OFF + (long)m * KOUT + k] = 0.f;
        }
    }
}

// ---------- main GEMM: 128x128 tile, BK=64, XOR LDS swizzle, XCD swizzle ----
__global__ __launch_bounds__(256) void stft_gemm(const ushort_t* __restrict__ xp,
                                                 const ushort_t* __restrict__ wbt,
                                                 float* __restrict__ out) {
    __shared__ __align__(16) ushort_t As[128 * 64];   // 16 KB, swizzled granules
    __shared__ __align__(16) ushort_t Bs[128 * 64];   // 16 KB

    const int tid = threadIdx.x;
    // XCD-aware mapping: round-robin XCD = f%8; XCD j owns n-tiles {2j,2j+1},
    // sweeps m with both n-tiles adjacent -> per-XCD L2 working set ~1-2 MB
    const int f   = blockIdx.x;            // 0..1263
    const int xcd = f & 7;
    const int w   = f >> 3;                // 0..157
    const int n0  = (2 * xcd + (w & 1)) * 128;
    const int m0  = (w >> 1) * 128;        // 0..78

    // staging source offsets: slot s = j*256+tid -> row=s>>3, phys granule=s&7,
    // logical granule g = (s&7) ^ (row&7); source k-offset = g*8
    int baseA[4], baseB[4];
#pragma unroll
    for (int j = 0; j < 4; ++j) {
        int slot = j * 256 + tid;
        int row  = slot >> 3;
        int g    = (slot & 7) ^ (row & 7);
        int m = m0 + row; if (m > MTOT - 1) m = MTOT - 1;   // clamp; stores guarded
        int b = m / TFR;
        int t = m - b * TFR;
        baseA[j] = b * LP + t * 512 + g * 8;
        baseB[j] = (n0 + row) * KD + g * 8;                 // n0+row < 2048 always
    }

    const int wave = tid >> 6;
    const int lane = tid & 63;
    const int wm = (wave >> 1) * 64;
    const int wn = (wave & 1) * 64;
    const int lm = lane & 15;
    const int quad = lane >> 4;

    float4v acc[4][4];
#pragma unroll
    for (int mi = 0; mi < 4; ++mi)
#pragma unroll
        for (int ni = 0; ni < 4; ++ni)
            acc[mi][ni] = (float4v){0.f, 0.f, 0.f, 0.f};

    for (int k0 = 0; k0 < KD; k0 += 64) {
        __syncthreads();                          // prior ds_reads done
#pragma unroll
        for (int j = 0; j < 4; ++j)
            async_copy16(xp + baseA[j] + k0, (char*)As + (j * 256 + tid) * 16);
#pragma unroll
        for (int j = 0; j < 4; ++j)
            async_copy16(wbt + baseB[j] + k0, (char*)Bs + (j * 256 + tid) * 16);
        __syncthreads();                          // drains vmcnt

#pragma unroll
        for (int kk = 0; kk < 2; ++kk) {
            short8 af[4], bf[4];
#pragma unroll
            for (int mi = 0; mi < 4; ++mi) {
                int row = wm + mi * 16 + lm;
                int pg  = (kk * 4 + quad) ^ (row & 7);
                af[mi] = *(const short8*)&As[row * 64 + pg * 8];
            }
#pragma unroll
            for (int ni = 0; ni < 4; ++ni) {
                int row = wn + ni * 16 + lm;
                int pg  = (kk * 4 + quad) ^ (row & 7);
                bf[ni] = *(const short8*)&Bs[row * 64 + pg * 8];
            }
#pragma unroll
            for (int mi = 0; mi < 4; ++mi)
#pragma unroll
                for (int ni = 0; ni < 4; ++ni)
                    acc[mi][ni] = __builtin_amdgcn_mfma_f32_16x16x32_bf16(
                        af[mi], bf[ni], acc[mi][ni], 0, 0, 0);
        }
    }

    // epilogue: C/D layout col=lane&15 (n), row=quad*4+reg (m); fp32 out
#pragma unroll
    for (int mi = 0; mi < 4; ++mi) {
#pragma unroll
        for (int ni = 0; ni < 4; ++ni) {
            int n = n0 + wn + ni * 16 + lm;           // < 2048 always
            long nbase = (n < KOUT) ? (long)n : (IMAG_OFF + (n - 1024));
#pragma unroll
            for (int rg = 0; rg < 4; ++rg) {
                int m = m0 + wm + mi * 16 + quad * 4 + rg;
                if (m < MTOT)
                    out[nbase + (long)m * KOUT] = acc[mi][ni][rg];
            }
        }
    }
}

extern "C" void kernel_launch(void* const* d_in, const int* in_sizes, int n_in,
                              void* d_out, int out_size, void* d_ws, size_t ws_size,
                              hipStream_t stream) {
    const float* x  = (const float*)d_in[0];     // fp32 (16, 320000)
    const float* wr = (const float*)d_in[1];     // fp32 (2048, 1025)
    const float* wi = (const float*)d_in[2];     // fp32 (2048, 1025)
    float* out = (float*)d_out;                  // fp32, 2*16*626*1025

    ushort_t* xp  = (ushort_t*)d_ws;             // 16*322048 bf16 = 10.3 MB
    ushort_t* wbt = xp + BATCH * LP;             // 2048*2048 bf16 =  8.4 MB

    prep<<<XP_BLOCKS + WBT_BLOCKS + ZB_BLOCKS, 256, 0, stream>>>(x, wr, wi, xp, wbt, out);

    stft_gemm<<<79 * 16, 256, 0, stream>>>(xp, wbt, out);   // 1264 blocks, XCD-swizzled
}